// Round 1
// baseline (266.594 us; speedup 1.0000x reference)
//
#include <hip/hip_runtime.h>

typedef unsigned short u16;
typedef unsigned int u32;

#define N_NODES 100000
#define N_EDGES 50000
#define C 128
#define G_GEMM 1563   // 1563 blocks * 4 waves = 6252 tiles >= 6250
#define DONE 0xFFFFFFFFu

static __device__ __forceinline__ float bf2f(u16 h) {
    u32 u = ((u32)h) << 16;
    float f;
    __builtin_memcpy(&f, &u, 4);
    return f;
}

static __device__ __forceinline__ u16 f2bf(float f) {
    u32 u;
    __builtin_memcpy(&u, &f, 4);
    return (u16)((u + 0x7fffu + ((u >> 16) & 1u)) >> 16);  // RNE
}

typedef short s16x8 __attribute__((ext_vector_type(8)));
typedef float f32x4 __attribute__((ext_vector_type(4)));

// ---------------- W transpose -> bf16: Wt[oc][k] = bf16(W[k][oc]) ----------
__global__ void transpose_w(const float* __restrict__ W, u16* __restrict__ Wt) {
    int idx = blockIdx.x * 256 + threadIdx.x;  // 16384 total
    int k = idx >> 7, oc = idx & 127;
    Wt[oc * 128 + k] = f2bf(W[k * 128 + oc]);
}

// ---------------- fused: list build (blocks < nBuild) + MFMA GEMM ----------
// Build blocks FIRST: the 1M scattered atomicExch ops start immediately and
// overlap the GEMM instead of trailing it (atomic-tail theory, round 1).
// Lists are split into 2 sublists per edge/node (head[2*e + (i&1)]) to halve
// chase depth in the gather kernels; atomic count unchanged.
// GEMM: xw[n][oc] = x[n][:] . W[:][oc], bf16 out. One wave per 16-row tile;
// A[m=lane&15][k=quad*8+j]; D col=lane&15, row=quad*4+reg (verified m89/m91).
__global__ __launch_bounds__(256) void fused_gemm_build(
    const float* __restrict__ x, const u16* __restrict__ Wt,
    u16* __restrict__ xw,
    const int* __restrict__ ni, const int* __restrict__ ei,
    u32* __restrict__ headE, u32* __restrict__ headN,
    uint2* __restrict__ pairE, uint2* __restrict__ pairN,
    int nnz, int nBuild) {
    if ((int)blockIdx.x < nBuild) {
        int i = blockIdx.x * 256 + threadIdx.x;
        if (i < nnz) {
            int n = ni[i], e = ei[i];
            int sub = i & 1;
            u32 oldE = atomicExch(&headE[e * 2 + sub], (u32)i);
            pairE[i] = make_uint2(oldE, (u32)n);
            u32 oldN = atomicExch(&headN[n * 2 + sub], (u32)i);
            pairN[i] = make_uint2(oldN, (u32)e);
        }
    } else {
        int wave = threadIdx.x >> 6;
        int tile = (blockIdx.x - nBuild) * 4 + wave;
        if (tile >= 6250) return;
        int lane = threadIdx.x & 63;
        int m = lane & 15;
        int quad = lane >> 4;
        int row0 = tile * 16;

        f32x4 acc[8];
#pragma unroll
        for (int nt = 0; nt < 8; ++nt) acc[nt] = (f32x4){0.f, 0.f, 0.f, 0.f};

        for (int k0 = 0; k0 < 128; k0 += 32) {
            int kb = k0 + quad * 8;
            const float* p = x + (size_t)(row0 + m) * C + kb;
            float4 v0 = *(const float4*)p;
            float4 v1 = *(const float4*)(p + 4);
            union { uint4 u; s16x8 v; } a;
            a.u.x = (u32)f2bf(v0.x) | ((u32)f2bf(v0.y) << 16);
            a.u.y = (u32)f2bf(v0.z) | ((u32)f2bf(v0.w) << 16);
            a.u.z = (u32)f2bf(v1.x) | ((u32)f2bf(v1.y) << 16);
            a.u.w = (u32)f2bf(v1.z) | ((u32)f2bf(v1.w) << 16);
#pragma unroll
            for (int nt = 0; nt < 8; ++nt) {
                union { uint4 u; s16x8 v; } b;
                b.u = *(const uint4*)(Wt + (size_t)(nt * 16 + m) * C + kb);
                acc[nt] = __builtin_amdgcn_mfma_f32_16x16x32_bf16(a.v, b.v, acc[nt], 0, 0, 0);
            }
        }

#pragma unroll
        for (int nt = 0; nt < 8; ++nt) {
#pragma unroll
            for (int r = 0; r < 4; ++r) {
                int row = row0 + quad * 4 + r;
                xw[(size_t)row * C + nt * 16 + m] = f2bf(acc[nt][r]);
            }
        }
    }
}

// ---------------- edge gather: 4 edges per wave, 2 sublists each ----------
// 8 concurrent chains of ~half depth -> 4x better latency profile vs the
// previous 4-chain/full-depth loop. ef[e] = bf16(B^-1_e * sum xw[nodes of e]);
// lane owns channels {2l, 2l+1}. Chase state is wave-uniform -> uniform branches.
__global__ __launch_bounds__(256) void edge_gather_k(const u16* __restrict__ xw,
                                                     const u32* __restrict__ headE,
                                                     const uint2* __restrict__ pairE,
                                                     u16* __restrict__ ef) {
    int wid = blockIdx.x * 4 + (threadIdx.x >> 6);
    int e0 = wid * 4;
    if (e0 >= N_EDGES) return;
    int lane = threadIdx.x & 63;

    u32 j0 = headE[e0 * 2 + 0];
    u32 j1 = headE[e0 * 2 + 1];
    u32 j2 = DONE, j3 = DONE, j4 = DONE, j5 = DONE, j6 = DONE, j7 = DONE;
    if (e0 + 1 < N_EDGES) { j2 = headE[e0 * 2 + 2]; j3 = headE[e0 * 2 + 3]; }
    if (e0 + 2 < N_EDGES) { j4 = headE[e0 * 2 + 4]; j5 = headE[e0 * 2 + 5]; }
    if (e0 + 3 < N_EDGES) { j6 = headE[e0 * 2 + 6]; j7 = headE[e0 * 2 + 7]; }

    float a0x = 0.f, a0y = 0.f, a1x = 0.f, a1y = 0.f;
    float a2x = 0.f, a2y = 0.f, a3x = 0.f, a3y = 0.f;
    int c0 = 0, c1 = 0, c2 = 0, c3 = 0;

    while ((j0 != DONE) | (j1 != DONE) | (j2 != DONE) | (j3 != DONE) |
           (j4 != DONE) | (j5 != DONE) | (j6 != DONE) | (j7 != DONE)) {
        uint2 p0, p1, p2, p3, p4, p5, p6, p7;
        if (j0 != DONE) p0 = pairE[j0];
        if (j1 != DONE) p1 = pairE[j1];
        if (j2 != DONE) p2 = pairE[j2];
        if (j3 != DONE) p3 = pairE[j3];
        if (j4 != DONE) p4 = pairE[j4];
        if (j5 != DONE) p5 = pairE[j5];
        if (j6 != DONE) p6 = pairE[j6];
        if (j7 != DONE) p7 = pairE[j7];
        if (j0 != DONE) {
            u32 u = ((const u32*)(xw + (size_t)p0.y * C))[lane];
            a0x += bf2f((u16)(u & 0xffffu)); a0y += bf2f((u16)(u >> 16));
            c0++; j0 = p0.x;
        }
        if (j1 != DONE) {
            u32 u = ((const u32*)(xw + (size_t)p1.y * C))[lane];
            a0x += bf2f((u16)(u & 0xffffu)); a0y += bf2f((u16)(u >> 16));
            c0++; j1 = p1.x;
        }
        if (j2 != DONE) {
            u32 u = ((const u32*)(xw + (size_t)p2.y * C))[lane];
            a1x += bf2f((u16)(u & 0xffffu)); a1y += bf2f((u16)(u >> 16));
            c1++; j2 = p2.x;
        }
        if (j3 != DONE) {
            u32 u = ((const u32*)(xw + (size_t)p3.y * C))[lane];
            a1x += bf2f((u16)(u & 0xffffu)); a1y += bf2f((u16)(u >> 16));
            c1++; j3 = p3.x;
        }
        if (j4 != DONE) {
            u32 u = ((const u32*)(xw + (size_t)p4.y * C))[lane];
            a2x += bf2f((u16)(u & 0xffffu)); a2y += bf2f((u16)(u >> 16));
            c2++; j4 = p4.x;
        }
        if (j5 != DONE) {
            u32 u = ((const u32*)(xw + (size_t)p5.y * C))[lane];
            a2x += bf2f((u16)(u & 0xffffu)); a2y += bf2f((u16)(u >> 16));
            c2++; j5 = p5.x;
        }
        if (j6 != DONE) {
            u32 u = ((const u32*)(xw + (size_t)p6.y * C))[lane];
            a3x += bf2f((u16)(u & 0xffffu)); a3y += bf2f((u16)(u >> 16));
            c3++; j6 = p6.x;
        }
        if (j7 != DONE) {
            u32 u = ((const u32*)(xw + (size_t)p7.y * C))[lane];
            a3x += bf2f((u16)(u & 0xffffu)); a3y += bf2f((u16)(u >> 16));
            c3++; j7 = p7.x;
        }
    }

    float s0 = c0 ? 1.f / (float)c0 : 0.f;
    float s1 = c1 ? 1.f / (float)c1 : 0.f;
    float s2 = c2 ? 1.f / (float)c2 : 0.f;
    float s3 = c3 ? 1.f / (float)c3 : 0.f;
    ((u32*)(ef + (size_t)e0 * C))[lane] =
        (u32)f2bf(a0x * s0) | ((u32)f2bf(a0y * s0) << 16);
    if (e0 + 1 < N_EDGES)
        ((u32*)(ef + (size_t)(e0 + 1) * C))[lane] =
            (u32)f2bf(a1x * s1) | ((u32)f2bf(a1y * s1) << 16);
    if (e0 + 2 < N_EDGES)
        ((u32*)(ef + (size_t)(e0 + 2) * C))[lane] =
            (u32)f2bf(a2x * s2) | ((u32)f2bf(a2y * s2) << 16);
    if (e0 + 3 < N_EDGES)
        ((u32*)(ef + (size_t)(e0 + 3) * C))[lane] =
            (u32)f2bf(a3x * s3) | ((u32)f2bf(a3y * s3) << 16);
}

// ---------------- node gather: 4 nodes per wave, 2 sublists each ----------
// out[v] = f32( D^-1_v * sum ef[edges of v] + b )
__global__ __launch_bounds__(256) void node_gather_k(const u16* __restrict__ ef,
                                                     const u32* __restrict__ headN,
                                                     const uint2* __restrict__ pairN,
                                                     const float* __restrict__ bias,
                                                     float* __restrict__ out) {
    int wid = blockIdx.x * 4 + (threadIdx.x >> 6);
    int v0 = wid * 4;
    if (v0 >= N_NODES) return;
    int lane = threadIdx.x & 63;

    u32 j0 = headN[v0 * 2 + 0];
    u32 j1 = headN[v0 * 2 + 1];
    u32 j2 = DONE, j3 = DONE, j4 = DONE, j5 = DONE, j6 = DONE, j7 = DONE;
    if (v0 + 1 < N_NODES) { j2 = headN[v0 * 2 + 2]; j3 = headN[v0 * 2 + 3]; }
    if (v0 + 2 < N_NODES) { j4 = headN[v0 * 2 + 4]; j5 = headN[v0 * 2 + 5]; }
    if (v0 + 3 < N_NODES) { j6 = headN[v0 * 2 + 6]; j7 = headN[v0 * 2 + 7]; }

    float a0x = 0.f, a0y = 0.f, a1x = 0.f, a1y = 0.f;
    float a2x = 0.f, a2y = 0.f, a3x = 0.f, a3y = 0.f;
    int c0 = 0, c1 = 0, c2 = 0, c3 = 0;

    while ((j0 != DONE) | (j1 != DONE) | (j2 != DONE) | (j3 != DONE) |
           (j4 != DONE) | (j5 != DONE) | (j6 != DONE) | (j7 != DONE)) {
        uint2 p0, p1, p2, p3, p4, p5, p6, p7;
        if (j0 != DONE) p0 = pairN[j0];
        if (j1 != DONE) p1 = pairN[j1];
        if (j2 != DONE) p2 = pairN[j2];
        if (j3 != DONE) p3 = pairN[j3];
        if (j4 != DONE) p4 = pairN[j4];
        if (j5 != DONE) p5 = pairN[j5];
        if (j6 != DONE) p6 = pairN[j6];
        if (j7 != DONE) p7 = pairN[j7];
        if (j0 != DONE) {
            u32 u = ((const u32*)(ef + (size_t)p0.y * C))[lane];
            a0x += bf2f((u16)(u & 0xffffu)); a0y += bf2f((u16)(u >> 16));
            c0++; j0 = p0.x;
        }
        if (j1 != DONE) {
            u32 u = ((const u32*)(ef + (size_t)p1.y * C))[lane];
            a0x += bf2f((u16)(u & 0xffffu)); a0y += bf2f((u16)(u >> 16));
            c0++; j1 = p1.x;
        }
        if (j2 != DONE) {
            u32 u = ((const u32*)(ef + (size_t)p2.y * C))[lane];
            a1x += bf2f((u16)(u & 0xffffu)); a1y += bf2f((u16)(u >> 16));
            c1++; j2 = p2.x;
        }
        if (j3 != DONE) {
            u32 u = ((const u32*)(ef + (size_t)p3.y * C))[lane];
            a1x += bf2f((u16)(u & 0xffffu)); a1y += bf2f((u16)(u >> 16));
            c1++; j3 = p3.x;
        }
        if (j4 != DONE) {
            u32 u = ((const u32*)(ef + (size_t)p4.y * C))[lane];
            a2x += bf2f((u16)(u & 0xffffu)); a2y += bf2f((u16)(u >> 16));
            c2++; j4 = p4.x;
        }
        if (j5 != DONE) {
            u32 u = ((const u32*)(ef + (size_t)p5.y * C))[lane];
            a2x += bf2f((u16)(u & 0xffffu)); a2y += bf2f((u16)(u >> 16));
            c2++; j5 = p5.x;
        }
        if (j6 != DONE) {
            u32 u = ((const u32*)(ef + (size_t)p6.y * C))[lane];
            a3x += bf2f((u16)(u & 0xffffu)); a3y += bf2f((u16)(u >> 16));
            c3++; j6 = p6.x;
        }
        if (j7 != DONE) {
            u32 u = ((const u32*)(ef + (size_t)p7.y * C))[lane];
            a3x += bf2f((u16)(u & 0xffffu)); a3y += bf2f((u16)(u >> 16));
            c3++; j7 = p7.x;
        }
    }

    float b0 = bias[2 * lane], b1 = bias[2 * lane + 1];
    float s0 = c0 ? 1.f / (float)c0 : 0.f;
    float s1 = c1 ? 1.f / (float)c1 : 0.f;
    float s2 = c2 ? 1.f / (float)c2 : 0.f;
    float s3 = c3 ? 1.f / (float)c3 : 0.f;
    float2 r;
    r.x = a0x * s0 + b0; r.y = a0y * s0 + b1;
    ((float2*)(out + (size_t)v0 * C))[lane] = r;
    if (v0 + 1 < N_NODES) {
        r.x = a1x * s1 + b0; r.y = a1y * s1 + b1;
        ((float2*)(out + (size_t)(v0 + 1) * C))[lane] = r;
    }
    if (v0 + 2 < N_NODES) {
        r.x = a2x * s2 + b0; r.y = a2y * s2 + b1;
        ((float2*)(out + (size_t)(v0 + 2) * C))[lane] = r;
    }
    if (v0 + 3 < N_NODES) {
        r.x = a3x * s3 + b0; r.y = a3y * s3 + b1;
        ((float2*)(out + (size_t)(v0 + 3) * C))[lane] = r;
    }
}

extern "C" void kernel_launch(void* const* d_in, const int* in_sizes, int n_in,
                              void* d_out, int out_size, void* d_ws, size_t ws_size,
                              hipStream_t stream) {
    const float* x = (const float*)d_in[0];     // [N_NODES,128] f32
    const int* node_idx = (const int*)d_in[1];  // [2, NNZ] row-major int32
    const int nnz = in_sizes[1] / 2;
    const int* edge_idx = node_idx + nnz;
    const float* W = (const float*)d_in[2];     // [128,128] f32
    const float* bias = (const float*)d_in[3];  // [128] f32
    float* out = (float*)d_out;                 // [N_NODES,128] f32

    // workspace layout (~18 MB; head tables are 2x for the sublist split)
    u16* Wt = (u16*)d_ws;                            // 16384 u16 (32 KB)
    u16* ef = Wt + 16384;                            // 6.4M u16 (12.8 MB)
    u32* headE = (u32*)(ef + (size_t)N_EDGES * C);   // 2*50000 u32 (400 KB)
    u32* headN = headE + 2 * N_EDGES;                // 2*100000 u32 (800 KB)
    uint2* pairN = (uint2*)(headN + 2 * N_NODES);    // nnz * 8B (4 MB)

    // d_out (51.2 MB f32) doubles as scratch:
    //   [0, 25.6 MB):    xw bf16  — consumed by edge_gather
    //   [25.6, 29.6 MB): pairE    — consumed by edge_gather
    // node_gather then overwrites the whole buffer with the f32 output.
    u16* xw = (u16*)d_out;
    uint2* pairE = (uint2*)((char*)d_out + (size_t)N_NODES * C * 2);

    int nBuild = (nnz + 255) / 256;

    hipMemsetAsync(headE, 0xFF, (size_t)(2 * N_EDGES + 2 * N_NODES) * 4, stream);
    transpose_w<<<64, 256, 0, stream>>>(W, Wt);
    fused_gemm_build<<<nBuild + G_GEMM, 256, 0, stream>>>(
        x, Wt, xw, node_idx, edge_idx, headE, headN, pairE, pairN, nnz, nBuild);
    // edges: 12500 waves (4 edges each), 4 waves/block
    edge_gather_k<<<(N_EDGES + 15) / 16, 256, 0, stream>>>(xw, headE, pairE, ef);
    // nodes: 25000 waves (4 nodes each), 4 waves/block
    node_gather_k<<<(N_NODES + 15) / 16, 256, 0, stream>>>(ef, headN, pairN, bias, out);
}